// Round 13
// baseline (209.713 us; speedup 1.0000x reference)
//
#include <hip/hip_runtime.h>
#include <hip/hip_bf16.h>

// WeightedSigLipLoss: N=8192 rows, C=6 classes, D=512 features.
// loss[n] = sum_m softplus(agree[n,m]*(t*sim[n,m]+b)) * w[n]/sum(w)
// sim   = normalize(features) @ normalize(features)^T  (symmetric, bf16 1-pass)
// agree = 2 * targets @ targets^T - 1  (exact fp32 dot6 in epilogue)
// Round 13: REGISTER-CLASS fix. m69: waves/CU halve at total-reg (VGPR+AGPR
// unified) {64,128,256}. Dual-acc (212 regs) pinned every prior round to the
// 256-class = 2 blocks/CU; r5's 132 was 4 over the 128 line (why its dot6
// showed no overlap benefit). This round: accS only (64 AGPR) +
// __launch_bounds__(256,4) forcing <=128 total + 32KB single-buffer LDS
// -> 4 blocks/CU, 16 waves. Keep r11 supertile decode + r12 fpack swizzle
// (conflict-free ds_read; at 4-block LDS pressure 16-way conflicts would
// saturate the LDS pipe). agree = exact dot6 epilogue, VALU hidden by
// co-resident blocks. tpA/tpB deleted.

#define NROW 8192
#define DIM  512
#define NCLS 6

#define BM 128
#define BK 64
#define NB (NROW / BM)           // 64 block-rows
#define NTRI (NB * (NB + 1) / 2) // 2080 upper-tri blocks = 8 * 260 (XCD chunks)
#define NSTG 8                   // 8 K-chunks of 64 (K=512)

typedef short s16x8 __attribute__((ext_vector_type(8)));
typedef float f32x4 __attribute__((ext_vector_type(4)));

static __device__ __forceinline__ ushort f2bf(float x) {
    __hip_bfloat16 h = __float2bfloat16(x);
    union { __hip_bfloat16 h; ushort u; } c; c.h = h; return c.u;
}

// ---------------- kernel 1: normalize + bf16 (chunk-swizzled) + wsum parts ----------------
// fpack[n][512] bf16, 16B chunks within each row stored at elem-offset ^
// ((row&7)<<3). After linear global_load_lds staging the LDS tile is
// swizzled; reads XOR the same key -> conflict-free (r12-proven, 49x drop).
__global__ __launch_bounds__(256) void k_prep(const float* __restrict__ feat,
                                              const float* __restrict__ w,
                                              ushort* __restrict__ fpack,
                                              float* __restrict__ partial,
                                              float* __restrict__ wpart) {
    const int wave = threadIdx.x >> 6, lane = threadIdx.x & 63;
    const int row = blockIdx.x * 4 + wave;
    const float* fr = feat + (size_t)row * DIM;
    float4 v0 = *(const float4*)(fr + lane * 4);
    float4 v1 = *(const float4*)(fr + 256 + lane * 4);
    float ss = v0.x*v0.x + v0.y*v0.y + v0.z*v0.z + v0.w*v0.w
             + v1.x*v1.x + v1.y*v1.y + v1.z*v1.z + v1.w*v1.w;
#pragma unroll
    for (int m = 1; m < 64; m <<= 1) ss += __shfl_xor(ss, m);
    const float inv = 1.f / fmaxf(sqrtf(ss), 1e-12f);

    float vals[8] = {v0.x, v0.y, v0.z, v0.w, v1.x, v1.y, v1.z, v1.w};
    ushort hi[8];
#pragma unroll
    for (int i = 0; i < 8; ++i) hi[i] = f2bf(vals[i] * inv);
    ushort* dst = fpack + (size_t)row * 512;
    const int sw = (row & 7) << 3;           // XOR key on elem-offset bits 3..5
    *(ushort4*)(dst + ((lane * 4) ^ sw))       = make_ushort4(hi[0], hi[1], hi[2], hi[3]);
    *(ushort4*)(dst + ((256 + lane * 4) ^ sw)) = make_ushort4(hi[4], hi[5], hi[6], hi[7]);

    __shared__ float red[4];
    if (lane == 0) {
        partial[row] = 0.f;
        red[wave] = w[row];
    }
    __syncthreads();
    if (threadIdx.x == 0)
        wpart[blockIdx.x] = red[0] + red[1] + red[2] + red[3];
}

// ---------------- staging via global_load_lds (16B), linear LDS dest [G21] ----------------
// 128 rows x 64 bf16 (src stride 512): 1024 chunks of 16B, 256 threads x 4.
__device__ __forceinline__ void stage_f(const ushort* __restrict__ src,
                                        ushort* lds, int tid) {
#pragma unroll
    for (int i = 0; i < 4; ++i) {
        int q = i * 256 + tid;
        int r = q >> 3, c = q & 7;
        __builtin_amdgcn_global_load_lds(
            (const __attribute__((address_space(1))) void*)(src + (size_t)r * 512 + c * 8),
            (__attribute__((address_space(3))) void*)(lds + q * 8),
            16, 0, 0);
    }
}

// ---------------- kernel 2: fused upper-tri GEMM + dot6-agree + softplus ----------------
// r3 single-buffer loop (stage -> sync -> 32 MFMA -> sync, 8 stages, BK=64),
// swizzled ds_reads, single 64-AGPR accumulator, <=128 total regs ->
// 4 blocks/CU: stage drains hide under co-resident blocks (m114).
__global__ __launch_bounds__(256, 4) void k_gemm(
    const ushort* __restrict__ fpack, const float* __restrict__ tgt,
    const float* __restrict__ tp, const float* __restrict__ bp,
    float* __restrict__ partial) {

    // ---- supertile-major decode + XCD chunk swizzle (r11-proven) ----
    const int orig = blockIdx.x;
    int b = (orig & 7) * (NTRI / 8) + (orig >> 3);
    int SI = 0, rem = b;
    while (rem >= 36 + (7 - SI) * 64) { rem -= 36 + (7 - SI) * 64; ++SI; }
    int bi, bj;
    if (rem < 36) {                       // diagonal supertile (SI,SI)
        int ii = 0;
        while (rem >= 8 - ii) { rem -= 8 - ii; ++ii; }
        bi = SI * 8 + ii;
        bj = SI * 8 + ii + rem;
    } else {                              // off-diagonal supertile (SI,SJ)
        const int r2 = rem - 36;
        const int SJ = SI + 1 + (r2 >> 6);
        const int idx = r2 & 63;
        bi = SI * 8 + (idx >> 3);
        bj = SJ * 8 + (idx & 7);
    }

    __shared__ ushort sA[BM * BK];   // 16 KB
    __shared__ ushort sB[BM * BK];   // 16 KB

    const int tid = threadIdx.x;
    const int lane = tid & 63;
    const int wave = tid >> 6;
    const int wr = wave >> 1, wc = wave & 1;   // 2x2 waves, 64x64 each

    const float tt = *tp, bb = *bp;

    f32x4 acc[4][4];
#pragma unroll
    for (int i = 0; i < 4; ++i)
#pragma unroll
        for (int j = 0; j < 4; ++j)
            acc[i][j] = (f32x4){0.f, 0.f, 0.f, 0.f};

    const ushort* baseA = fpack + (size_t)(bi * BM) * 512;
    const ushort* baseB = fpack + (size_t)(bj * BM) * 512;
    const int rr = lane & 15;
    const int ksw = (lane & 7) << 3;          // read-side swizzle key

    for (int s = 0; s < NSTG; ++s) {
        stage_f(baseA + s * 64, &sA[0], tid);
        stage_f(baseB + s * 64, &sB[0], tid);
        __syncthreads();
#pragma unroll
        for (int kk = 0; kk < 2; ++kk) {
            s16x8 af[4], bg[4];
            const int kb = (kk * 32 + (lane >> 4) * 8) ^ ksw;
#pragma unroll
            for (int i = 0; i < 4; ++i)
                af[i] = *(const s16x8*)(&sA[(wr * 64 + i * 16 + rr) * BK + kb]);
#pragma unroll
            for (int j = 0; j < 4; ++j)
                bg[j] = *(const s16x8*)(&sB[(wc * 64 + j * 16 + rr) * BK + kb]);
#pragma unroll
            for (int i = 0; i < 4; ++i)
#pragma unroll
                for (int j = 0; j < 4; ++j)
                    acc[i][j] = __builtin_amdgcn_mfma_f32_16x16x32_bf16(
                        af[i], bg[j], acc[i][j], 0, 0, 0);
        }
        __syncthreads();
    }

    // ---- stage targets (fp32, exact agree) into the freed LDS ----
    float* sTA = (float*)&sA[0];   // 128 x 6 floats = 3 KB
    float* sTB = (float*)&sB[0];
    for (int q = tid; q < BM * NCLS; q += 256) {
        sTA[q] = tgt[(size_t)(bi * BM) * NCLS + q];
        sTB[q] = tgt[(size_t)(bj * BM) * NCLS + q];
    }
    __syncthreads();

    // ---- epilogue: agree (dot6) + softplus + row/col partial sums ----
    // C/D layout (m89): col = lane&15, row = (lane>>4)*4 + r
    float tcol[4][NCLS];
#pragma unroll
    for (int j = 0; j < 4; ++j) {
        const int col = wc * 64 + j * 16 + (lane & 15);
#pragma unroll
        for (int c = 0; c < NCLS; ++c) tcol[j][c] = sTB[col * NCLS + c];
    }

    float rowsum[4][4];
    float colsum[4];
#pragma unroll
    for (int i = 0; i < 4; ++i)
#pragma unroll
        for (int r = 0; r < 4; ++r) rowsum[i][r] = 0.f;
#pragma unroll
    for (int j = 0; j < 4; ++j) colsum[j] = 0.f;

#pragma unroll
    for (int i = 0; i < 4; ++i)
#pragma unroll
        for (int r = 0; r < 4; ++r) {
            const int row = wr * 64 + i * 16 + (lane >> 4) * 4 + r;
            float trow[NCLS];
#pragma unroll
            for (int c = 0; c < NCLS; ++c) trow[c] = sTA[row * NCLS + c];
#pragma unroll
            for (int j = 0; j < 4; ++j) {
                float d = 0.f;
#pragma unroll
                for (int c = 0; c < NCLS; ++c) d = fmaf(trow[c], tcol[j][c], d);
                const float agree = fmaf(2.f, d, -1.f);
                const float e = agree * fmaf(tt, acc[i][j][r], bb);
                // softplus(e), stable: max(e,0) + log(1+exp(-|e|))
                const float sp = fmaxf(e, 0.f) + __logf(1.f + __expf(-fabsf(e)));
                rowsum[i][r] += sp;
                colsum[j] += sp;
            }
        }

    // row sums: reduce across the 16 col-lanes (bits 0..3)
#pragma unroll
    for (int i = 0; i < 4; ++i)
#pragma unroll
        for (int r = 0; r < 4; ++r) {
            float v = rowsum[i][r];
            v += __shfl_xor(v, 1); v += __shfl_xor(v, 2);
            v += __shfl_xor(v, 4); v += __shfl_xor(v, 8);
            if ((lane & 15) == 0)
                atomicAdd(&partial[bi * BM + wr * 64 + i * 16 + (lane >> 4) * 4 + r], v);
        }
    // col sums (transpose contribution), off-diagonal blocks only
    if (bi != bj) {
#pragma unroll
        for (int j = 0; j < 4; ++j) {
            float v = colsum[j];
            v += __shfl_xor(v, 16); v += __shfl_xor(v, 32);
            if (lane < 16)
                atomicAdd(&partial[bj * BM + wc * 64 + j * 16 + lane], v);
        }
    }
}

// ---------------- kernel 3: wsum reduce + final scale ----------------
// loss[n] = (1/N)*rowsum[n] * w[n] / (wsum/N) = rowsum[n] * w[n] / wsum
__global__ __launch_bounds__(256) void k_final(const float* __restrict__ partial,
                                               const float* __restrict__ w,
                                               const float* __restrict__ wpart,
                                               float* __restrict__ out) {
    __shared__ float red[4];
    float s = 0.f;
    for (int i = threadIdx.x; i < NROW / 4; i += 256) s += wpart[i];
#pragma unroll
    for (int m = 1; m < 64; m <<= 1) s += __shfl_xor(s, m);
    if ((threadIdx.x & 63) == 0) red[threadIdx.x >> 6] = s;
    __syncthreads();
    const float wsum = red[0] + red[1] + red[2] + red[3];
    int i = blockIdx.x * 256 + threadIdx.x;
    out[i] = partial[i] * w[i] / wsum;
}

extern "C" void kernel_launch(void* const* d_in, const int* in_sizes, int n_in,
                              void* d_out, int out_size, void* d_ws, size_t ws_size,
                              hipStream_t stream) {
    // inputs: 0=logits(unused), 1=targets, 2=features, 3=weights, 4=t, 5=b
    const float* targets  = (const float*)d_in[1];
    const float* features = (const float*)d_in[2];
    const float* weights  = (const float*)d_in[3];
    const float* tp       = (const float*)d_in[4];
    const float* bp       = (const float*)d_in[5];
    float* out = (float*)d_out;

    // workspace layout (~8.1 MB)
    char* p = (char*)d_ws;
    ushort* fpack   = (ushort*)p; p += (size_t)NROW * 512 * sizeof(ushort); // 8 MB
    float*  partial = (float*)p;  p += (size_t)NROW * sizeof(float);        // 32 KB
    float*  wpart   = (float*)p;  p += (size_t)(NROW / 4) * sizeof(float);  // 8 KB

    k_prep<<<NROW / 4, 256, 0, stream>>>(features, weights, fpack, partial, wpart);
    k_gemm<<<NTRI, 256, 0, stream>>>(fpack, targets, tp, bp, partial);
    k_final<<<NROW / 256, 256, 0, stream>>>(partial, weights, wpart, out);
}